// Round 6
// baseline (111.026 us; speedup 1.0000x reference)
//
#include <hip/hip_runtime.h>

#define N_DIM   8
#define N_COMP  4
#define N_SYMB  16
#define UNROLL  8
#define THREADS 256

typedef float f32x4 __attribute__((ext_vector_type(4)));

// LDS tables:
//   s_ip4[ch]  (ch = comp*2 + half), 8 entries  -> 8 disjoint bank-quads, conflict-free
//   s_off4[e ^ (symb&1)] (e = symb*8 + ch), 128 entries, parity-swizzled so the
//   start bank-quad = comp*8 + (symb&1)*4 (8 quads, ~2-3-way aliasing on random gather)
template <bool GUARD>
__global__ __launch_bounds__(THREADS) void inv_affine_kernel(
    const float4* __restrict__ samples4,   // 2*n float4s
    const float*  __restrict__ mus_orig,   // (16, 32)
    const float*  __restrict__ mus,        // (16, 32)
    const float*  __restrict__ psi,        // (32,)
    const int*    __restrict__ idx_symb,   // (n,)
    const int*    __restrict__ idx_comp,   // (n,)
    float4*       __restrict__ out4,       // 2*n float4s
    int n2)                                // = 2*n
{
    __shared__ float4 s_ip4[N_COMP * 2];                // 8 entries
    __shared__ float4 s_off4[N_SYMB * N_COMP * 2];      // 128 entries, swizzled
    __shared__ float  s_ipsi[N_COMP * N_DIM];           // 32 floats scratch

    const int tid = threadIdx.x;

    if (tid < N_COMP * N_DIM) s_ipsi[tid] = 1.0f / psi[tid];
    __syncthreads();

    if (tid < N_COMP * 2) {
        float4 ip;
        float* ipf = (float*)&ip;
        #pragma unroll
        for (int j = 0; j < 4; ++j) ipf[j] = s_ipsi[tid * 4 + j];
        s_ip4[tid] = ip;
    }
    if (tid < N_SYMB * N_COMP * 2) {
        const int symb = tid >> 3;
        const int ch   = tid & 7;
        const int cd0  = ch * 4;
        float4 off;
        float* offf = (float*)&off;
        #pragma unroll
        for (int j = 0; j < 4; ++j) {
            offf[j] = fmaf(-mus[symb * 32 + cd0 + j], s_ipsi[cd0 + j],
                           mus_orig[symb * 32 + cd0 + j]);
        }
        s_off4[tid ^ (symb & 1)] = off;   // parity swizzle on the half-bit
    }
    __syncthreads();

    const int base = blockIdx.x * (THREADS * UNROLL) + tid;

    // Phase 1: issue ALL loads (independent -> VMEM pipe stays full)
    float4 s[UNROLL];
    int    ch_[UNROLL];
    int    eo_[UNROLL];
    #pragma unroll
    for (int k = 0; k < UNROLL; ++k) {
        int g = base + k * THREADS;
        if (GUARD && g >= n2) g = 0;
        const int row  = g >> 1;
        const int symb = idx_symb[row];
        const int comp = idx_comp[row];
        s[k] = samples4[g];
        const int e = (symb << 3) + (comp << 1) + (g & 1);
        ch_[k] = (comp << 1) + (g & 1);
        eo_[k] = e ^ (symb & 1);
    }

    // Phase 2: LDS lookups + FMA + store
    #pragma unroll
    for (int k = 0; k < UNROLL; ++k) {
        const float4 ip  = s_ip4[ch_[k]];
        const float4 off = s_off4[eo_[k]];
        float4 o;
        o.x = fmaf(s[k].x, ip.x, off.x);
        o.y = fmaf(s[k].y, ip.y, off.y);
        o.z = fmaf(s[k].z, ip.z, off.z);
        o.w = fmaf(s[k].w, ip.w, off.w);
        const int g = base + k * THREADS;
        if (!GUARD || g < n2) {
            out4[g] = o;
        }
    }
}

extern "C" void kernel_launch(void* const* d_in, const int* in_sizes, int n_in,
                              void* d_out, int out_size, void* d_ws, size_t ws_size,
                              hipStream_t stream) {
    const float4* samples4 = (const float4*)d_in[0];
    const float*  mus_orig = (const float*)d_in[1];
    const float*  mus      = (const float*)d_in[2];
    const float*  psi      = (const float*)d_in[3];
    const int*    idx_symb = (const int*)d_in[4];
    const int*    idx_comp = (const int*)d_in[5];
    float4*       out4     = (float4*)d_out;

    const int n  = in_sizes[4];
    const int n2 = n * 2;

    const int per_block = THREADS * UNROLL;
    const int blocks = (n2 + per_block - 1) / per_block;

    if (blocks * per_block == n2) {
        inv_affine_kernel<false><<<blocks, THREADS, 0, stream>>>(
            samples4, mus_orig, mus, psi, idx_symb, idx_comp, out4, n2);
    } else {
        inv_affine_kernel<true><<<blocks, THREADS, 0, stream>>>(
            samples4, mus_orig, mus, psi, idx_symb, idx_comp, out4, n2);
    }
}

// Round 7
// 93.435 us; speedup vs baseline: 1.1883x; 1.1883x over previous
//
#include <hip/hip_runtime.h>

#define N_DIM   8
#define N_COMP  4
#define N_SYMB  16
#define UNROLL  8
#define THREADS 256

typedef float f32x4 __attribute__((ext_vector_type(4)));

// LDS tables:
//   s_ip4[ch]  (ch = comp*2 + half), 8 entries  -> 8 disjoint bank-quads, conflict-free
//   s_off4[e ^ (symb&1)] (e = symb*8 + ch), 128 entries, parity-swizzled so the
//   start bank-quad = comp*8 + (symb&1)*4 (8 quads, ~2-3-way aliasing on random gather)
template <bool GUARD>
__global__ __launch_bounds__(THREADS) void inv_affine_kernel(
    const float4* __restrict__ samples4,   // 2*n float4s
    const float*  __restrict__ mus_orig,   // (16, 32)
    const float*  __restrict__ mus,        // (16, 32)
    const float*  __restrict__ psi,        // (32,)
    const int*    __restrict__ idx_symb,   // (n,)
    const int*    __restrict__ idx_comp,   // (n,)
    float4*       __restrict__ out4,       // 2*n float4s
    int n2)                                // = 2*n
{
    __shared__ float4 s_ip4[N_COMP * 2];                // 8 entries
    __shared__ float4 s_off4[N_SYMB * N_COMP * 2];      // 128 entries, swizzled
    __shared__ float  s_ipsi[N_COMP * N_DIM];           // 32 floats scratch

    const int tid = threadIdx.x;

    if (tid < N_COMP * N_DIM) s_ipsi[tid] = 1.0f / psi[tid];
    __syncthreads();

    if (tid < N_COMP * 2) {
        float4 ip;
        float* ipf = (float*)&ip;
        #pragma unroll
        for (int j = 0; j < 4; ++j) ipf[j] = s_ipsi[tid * 4 + j];
        s_ip4[tid] = ip;
    }
    if (tid < N_SYMB * N_COMP * 2) {
        const int symb = tid >> 3;
        const int ch   = tid & 7;
        const int cd0  = ch * 4;
        float4 off;
        float* offf = (float*)&off;
        #pragma unroll
        for (int j = 0; j < 4; ++j) {
            offf[j] = fmaf(-mus[symb * 32 + cd0 + j], s_ipsi[cd0 + j],
                           mus_orig[symb * 32 + cd0 + j]);
        }
        s_off4[tid ^ (symb & 1)] = off;   // parity swizzle on the half-bit
    }
    __syncthreads();

    const int base = blockIdx.x * (THREADS * UNROLL) + tid;

    // Phase 1: issue ALL loads (independent -> VMEM pipe stays full).
    // samples: non-temporal (single-use stream, don't pollute L2).
    float4 s[UNROLL];
    int    ch_[UNROLL];
    int    eo_[UNROLL];
    #pragma unroll
    for (int k = 0; k < UNROLL; ++k) {
        int g = base + k * THREADS;
        if (GUARD && g >= n2) g = 0;
        const int row  = g >> 1;
        const int symb = idx_symb[row];
        const int comp = idx_comp[row];
        f32x4 sv = __builtin_nontemporal_load(
            reinterpret_cast<const f32x4*>(&samples4[g]));
        s[k] = *reinterpret_cast<const float4*>(&sv);
        const int e = (symb << 3) + (comp << 1) + (g & 1);
        ch_[k] = (comp << 1) + (g & 1);
        eo_[k] = e ^ (symb & 1);
    }

    // Phase 2: LDS lookups + FMA + nt store
    #pragma unroll
    for (int k = 0; k < UNROLL; ++k) {
        const float4 ip  = s_ip4[ch_[k]];
        const float4 off = s_off4[eo_[k]];
        f32x4 o;
        o.x = fmaf(s[k].x, ip.x, off.x);
        o.y = fmaf(s[k].y, ip.y, off.y);
        o.z = fmaf(s[k].z, ip.z, off.z);
        o.w = fmaf(s[k].w, ip.w, off.w);
        const int g = base + k * THREADS;
        if (!GUARD || g < n2) {
            __builtin_nontemporal_store(o, reinterpret_cast<f32x4*>(&out4[g]));
        }
    }
}

extern "C" void kernel_launch(void* const* d_in, const int* in_sizes, int n_in,
                              void* d_out, int out_size, void* d_ws, size_t ws_size,
                              hipStream_t stream) {
    const float4* samples4 = (const float4*)d_in[0];
    const float*  mus_orig = (const float*)d_in[1];
    const float*  mus      = (const float*)d_in[2];
    const float*  psi      = (const float*)d_in[3];
    const int*    idx_symb = (const int*)d_in[4];
    const int*    idx_comp = (const int*)d_in[5];
    float4*       out4     = (float4*)d_out;

    const int n  = in_sizes[4];
    const int n2 = n * 2;

    const int per_block = THREADS * UNROLL;
    const int blocks = (n2 + per_block - 1) / per_block;

    if (blocks * per_block == n2) {
        inv_affine_kernel<false><<<blocks, THREADS, 0, stream>>>(
            samples4, mus_orig, mus, psi, idx_symb, idx_comp, out4, n2);
    } else {
        inv_affine_kernel<true><<<blocks, THREADS, 0, stream>>>(
            samples4, mus_orig, mus, psi, idx_symb, idx_comp, out4, n2);
    }
}